// Round 5
// baseline (313.808 us; speedup 1.0000x reference)
//
#include <hip/hip_runtime.h>

// ROI Align (FPN multi-level), OUT=7, ratio=2.
// Round-9: R5-R8 all latency-bound; wave-shot designs pay one full
// issue->drain chain per 2-4 outputs and LDS footprint caps concurrency.
// Fix: PERSISTENT waves. Each wave owns (channel-pair, ROI-chunk) and
// marches ~62 ROI groups with a double-buffered LDS pipeline:
//   issue staging(m+1) [padded to exactly 10 global_load_lds],
//   s_waitcnt vmcnt(10)  (keeps m+1's flight airborne),
//   compute group m      (overlaps m+1's flight),
//   prefetch geometry(m+2) [compiler-tracked], store m, flip parity.
// Chain latency paid once per wave, not once per group. Unsafe ROIs
// (buffer-end overhang, ~1%) go to an atomic-compacted list handled by a
// small global-gather fallback kernel; the pipeline path never breaks its
// vmcnt accounting. Trailing vmcnt(0) drains tail stagings before exit.
// LDS: 2 waves x (2buf x 2units x 4.6KB + 1KB dump) = 38.9KB/block ->
// 4 blocks/CU -> 8 persistent waves/CU. Grid fixed at 1024 blocks.

#define NCH 256
#define POOL 7
#define NBIN 49
#define CAP 1152          // floats per unit footprint region (max ~1040)
#define TS 160            // u32 words per ROI table entry (640 B)
#define ITMAX 5           // max staging iterations (safe path)
#define PWPB 4            // precompute waves per block
#define DUMPF (4 * CAP)   // per-wave dump row offset (floats)
#define WREG (4 * CAP + 256) // per-wave LDS floats (2 bufs x 2 units + dump)

typedef __attribute__((address_space(3))) void       as3_void;
typedef __attribute__((address_space(1))) const void as1_void;
#define RFL(x) __builtin_amdgcn_readfirstlane(x)

// ---------------------------------------------------------------------------
// Per-ROI precompute: one wave per ROI. tab[m*TS..]:
//  [0] base_off (elems,c=0) [1] lvl   [2] HW   [3] W
//  [4] lpr  [5] Mg=ceil(2^16/lpr)  [6] rpi=64/lpr  [7] iters
//  [8] gstep=rpi*W  [9] lstepB=rpi*RS4*4  [10] (FH-1)*W  [11] safe
//  [12] FW  [13] RS4  [14] FH2  [15] Mg2
//  [16..71]  xtab[14] uint4 {xr, xp=min(xr+1,FW-1), wxl, wxh}
//  [72..127] ytab[14] uint4 {(ylo-ry0)*RS4, (yhi-ry0)*RS4, wyl, wyh}
//  [128..155] ytabW[14] uint2 {(ylo-ry0)*W, (yhi-ry0)*W}   (global-gather)
// Unsafe ROIs appended to list[] via atomic count.
// ---------------------------------------------------------------------------
__global__ __launch_bounds__(256) void roi_precompute_kernel(
    const float* __restrict__ boxes, const int* __restrict__ bidx,
    unsigned int* __restrict__ tab, unsigned int* __restrict__ list,
    unsigned int* __restrict__ cnt, int M)
{
    const int lane = threadIdx.x & 63;
    const int m = blockIdx.x * PWPB + (threadIdx.x >> 6);
    if (m >= M) return;

    float bx0 = boxes[4 * m + 0];
    float by0 = boxes[4 * m + 1];
    float bx1 = boxes[4 * m + 2];
    float by1 = boxes[4 * m + 3];

    float area = (bx1 - bx0) * (by1 - by0);
    float sz   = sqrtf(area);
    float lvlf = floorf(4.0f + log2f(sz / 224.0f + 1e-8f));
    lvlf = fminf(fmaxf(lvlf, 2.0f), 5.0f);
    int lvl = (int)lvlf - 2;

    int H, W; float scale;
    if (lvl == 0)      { H = 200; W = 304; scale = 0.25f;    }
    else if (lvl == 1) { H = 100; W = 152; scale = 0.125f;   }
    else if (lvl == 2) { H = 50;  W = 76;  scale = 0.0625f;  }
    else               { H = 25;  W = 38;  scale = 0.03125f; }

    float x0 = bx0 * scale - 0.5f;
    float y0 = by0 * scale - 0.5f;
    float bin_w = (bx1 * scale - 0.5f - x0) * (1.0f / 7.0f);
    float bin_h = (by1 * scale - 0.5f - y0) * (1.0f / 7.0f);

    int axis = lane >= 14;
    int s    = axis ? (lane - 14) : lane;
    float off = (float)(s >> 1) + ((s & 1) ? 0.75f : 0.25f);
    float cv    = axis ? (y0 + bin_h * off) : (x0 + bin_w * off);
    float size  = axis ? (float)H : (float)W;
    float valid = (cv >= -1.0f && cv <= size) ? 1.0f : 0.0f;
    float cc    = fmaxf(cv, 0.0f);
    float lo_f  = floorf(cc);
    bool  capd  = lo_f >= size - 1.0f;
    int   lo    = capd ? (int)size - 1 : (int)lo_f;
    int   hi    = capd ? lo : lo + 1;
    float l     = capd ? 0.0f : (cc - lo_f);
    float wlo   = (1.0f - l) * valid;
    float whi   = l * valid;

    int rx0 = __shfl(lo, 0);
    int rxe = __shfl(hi, 13);
    int ry0 = __shfl(lo, 14);
    int rye = __shfl(hi, 27);

    int FW  = rxe - rx0 + 1;
    int FH  = rye - ry0 + 1;
    int lpr = (FW + 3) >> 2;
    int RS4 = lpr << 2;
    int rpi = 64 / lpr;
    int iters = (FH + rpi - 1) / rpi;
    unsigned Mg  = (65536u   + (unsigned)lpr - 1u) / (unsigned)lpr;
    unsigned Mg2 = (4194304u + (unsigned)RS4 - 1u) / (unsigned)RS4;
    unsigned HW  = (unsigned)(H * W);
    unsigned base_off = (unsigned)bidx[m] * 256u * HW
                      + (unsigned)ry0 * (unsigned)W + (unsigned)rx0;
    int FH2 = FH;
    if (FH2 * RS4 > CAP) FH2 = CAP / RS4;
    // conservative (c=255) safety: clamped staging touches at most
    // src + (FH-1)*W + RS4; padded extent iters*rpi*RS4 must fit CAP.
    unsigned lastoff = base_off + 255u * HW
                     + (unsigned)(FH - 1) * (unsigned)W + (unsigned)RS4;
    int safe = (lastoff <= 2u * 256u * HW)
            && (iters * rpi * RS4 <= CAP)
            && (iters <= ITMAX);

    unsigned* t = tab + (size_t)m * TS;
    if (lane == 0) {
        t[0]  = base_off;
        t[1]  = (unsigned)lvl;
        t[2]  = HW;
        t[3]  = (unsigned)W;
        t[4]  = (unsigned)lpr;
        t[5]  = Mg;
        t[6]  = (unsigned)rpi;
        t[7]  = (unsigned)iters;
        t[8]  = (unsigned)(rpi * W);
        t[9]  = (unsigned)((rpi * RS4) << 2);
        t[10] = (unsigned)((FH - 1) * W);
        t[11] = (unsigned)safe;
        t[12] = (unsigned)FW;
        t[13] = (unsigned)RS4;
        t[14] = (unsigned)FH2;
        t[15] = Mg2;
        if (!safe) {
            unsigned i = atomicAdd(cnt, 1u);
            list[i] = (unsigned)m;
        }
    }
    if (lane < 28) {
        if (!axis) {
            int xr = lo - rx0;
            int xp = min(xr + 1, FW - 1);   // cap-x: weight 0, stay in row
            uint4 v;
            v.x = (unsigned)xr;
            v.y = (unsigned)xp;
            v.z = __float_as_uint(wlo);
            v.w = __float_as_uint(whi);
            *(uint4*)(t + 16 + 4 * s) = v;
        } else {
            uint4 v;
            v.x = (unsigned)((lo - ry0) * RS4);
            v.y = (unsigned)((hi - ry0) * RS4);
            v.z = __float_as_uint(wlo);
            v.w = __float_as_uint(whi);
            *(uint4*)(t + 72 + 4 * s) = v;
            uint2 vw;
            vw.x = (unsigned)((lo - ry0) * W);
            vw.y = (unsigned)((hi - ry0) * W);
            *(uint2*)(t + 128 + 2 * s) = vw;
        }
    }
}

// ---- staging: exactly 2*ITMAX=10 global_load_lds, dummies -> dump row ----
#define STAGE(S0_, S1_, S2_, P_) do {                                        \
    const int      lvl_   = RFL((int)(S0_).y);                               \
    const float*   fp_    = (lvl_ == 0) ? f0 : (lvl_ == 1) ? f1              \
                          : (lvl_ == 2) ? f2 : f3;                           \
    const unsigned HW_    = (S0_).z;                                         \
    const unsigned Wd_    = (S0_).w;                                         \
    const int      safe_  = RFL((int)(S2_).w);                               \
    const int      lpr_   = RFL((int)(S1_).x);                               \
    const unsigned Mg_    = (S1_).y;                                         \
    const int      rpi_   = RFL((int)(S1_).z);                               \
    const int      iters_ = RFL((int)(S1_).w);                               \
    const unsigned gstep_ = (S2_).x;                                         \
    const unsigned lstep_ = (unsigned)RFL((int)(S2_).y);                     \
    const unsigned fhw_   = (S2_).z;                                         \
    const float*   src_   = fp_ + (size_t)((S0_).x + (unsigned)c0 * HW_);    \
    int sfy_  = (int)(((unsigned)lane * Mg_) >> 16);                         \
    int sfx4_ = (lane - sfy_ * lpr_) << 2;                                   \
    if (sfy_ < rpi_) {                                                       \
        const float* gA_  = src_ + (unsigned)sfy_ * Wd_ + (unsigned)sfx4_;   \
        const float* gmA_ = src_ + fhw_ + (unsigned)sfx4_;                   \
        const float* gB_  = gA_ + HW_;                                       \
        const float* gmB_ = gmA_ + HW_;                                      \
        char* lA_  = (char*)&sF[w][(P_) * 2 * CAP];                          \
        char* lB_  = lA_ + CAP * 4;                                          \
        char* dmp_ = (char*)&sF[w][DUMPF];                                   \
        _Pragma("unroll")                                                    \
        for (int it_ = 0; it_ < ITMAX; ++it_) {                              \
            const float* pa_ = (gA_ > gmA_) ? gmA_ : gA_;                    \
            const float* pb_ = (gB_ > gmB_) ? gmB_ : gB_;                    \
            const float* qa_ = safe_ ? pa_ : (const float*)f0;               \
            const float* qb_ = safe_ ? pb_ : (const float*)f0;               \
            bool real_ = safe_ && (it_ < iters_);                            \
            char* wa_ = real_ ? lA_ : dmp_;                                  \
            char* wb_ = real_ ? lB_ : dmp_;                                  \
            __builtin_amdgcn_global_load_lds((as1_void*)qa_,                 \
                                             (as3_void*)wa_, 16, 0, 0);      \
            __builtin_amdgcn_global_load_lds((as1_void*)qb_,                 \
                                             (as3_void*)wb_, 16, 0, 0);      \
            gA_ += gstep_; gB_ += gstep_; lA_ += lstep_; lB_ += lstep_;      \
        }                                                                    \
    }                                                                        \
} while (0)

#define GEOM(MM_, X0_, X1_, Y0_, Y1_, S0_, S1_, S2_) do {                    \
    const unsigned* t_ = tab + (size_t)(MM_) * TS;                           \
    const uint4* xt_ = (const uint4*)(t_ + 16);                              \
    const uint4* yt_ = (const uint4*)(t_ + 72);                              \
    X0_ = xt_[2 * px];  X1_ = xt_[2 * px + 1];                               \
    Y0_ = yt_[2 * py];  Y1_ = yt_[2 * py + 1];                               \
    S0_ = *(const uint4*)(t_);                                               \
    S1_ = *(const uint4*)(t_ + 4);                                           \
    S2_ = *(const uint4*)(t_ + 8);                                           \
} while (0)

#define COMPUTE_STORE(X0_, X1_, Y0_, Y1_, S2_, P_, M_) do {                  \
    const int safe_ = RFL((int)(S2_).w);                                     \
    if (safe_) {                                                             \
        const float* FbA = &sF[w][(P_) * 2 * CAP];                           \
        const float* FbB = FbA + CAP;                                        \
        const unsigned xr0 = (X0_).x, xp0 = (X0_).y;                         \
        const unsigned xr1 = (X1_).x, xp1 = (X1_).y;                         \
        const float wxl0 = __uint_as_float((X0_).z);                         \
        const float wxh0 = __uint_as_float((X0_).w);                         \
        const float wxl1 = __uint_as_float((X1_).z);                         \
        const float wxh1 = __uint_as_float((X1_).w);                         \
        const unsigned ra = (Y0_).x, rb = (Y0_).y;                           \
        const unsigned rc = (Y1_).x, rd = (Y1_).y;                           \
        const float wy0 = __uint_as_float((Y0_).z);                          \
        const float wy1 = __uint_as_float((Y0_).w);                          \
        const float wy2 = __uint_as_float((Y1_).z);                          \
        const float wy3 = __uint_as_float((Y1_).w);                          \
        float a0 = FbA[ra + xr0] * wxl0 + FbA[ra + xp0] * wxh0               \
                 + FbA[ra + xr1] * wxl1 + FbA[ra + xp1] * wxh1;              \
        float a1 = FbA[rb + xr0] * wxl0 + FbA[rb + xp0] * wxh0               \
                 + FbA[rb + xr1] * wxl1 + FbA[rb + xp1] * wxh1;              \
        float a2 = FbA[rc + xr0] * wxl0 + FbA[rc + xp0] * wxh0               \
                 + FbA[rc + xr1] * wxl1 + FbA[rc + xp1] * wxh1;              \
        float a3 = FbA[rd + xr0] * wxl0 + FbA[rd + xp0] * wxh0               \
                 + FbA[rd + xr1] * wxl1 + FbA[rd + xp1] * wxh1;              \
        float accA = wy0 * a0 + wy1 * a1 + wy2 * a2 + wy3 * a3;              \
        float b0 = FbB[ra + xr0] * wxl0 + FbB[ra + xp0] * wxh0               \
                 + FbB[ra + xr1] * wxl1 + FbB[ra + xp1] * wxh1;              \
        float b1 = FbB[rb + xr0] * wxl0 + FbB[rb + xp0] * wxh0               \
                 + FbB[rb + xr1] * wxl1 + FbB[rb + xp1] * wxh1;              \
        float b2 = FbB[rc + xr0] * wxl0 + FbB[rc + xp0] * wxh0               \
                 + FbB[rc + xr1] * wxl1 + FbB[rc + xp1] * wxh1;              \
        float b3 = FbB[rd + xr0] * wxl0 + FbB[rd + xp0] * wxh0               \
                 + FbB[rd + xr1] * wxl1 + FbB[rd + xp1] * wxh1;              \
        float accB = wy0 * b0 + wy1 * b1 + wy2 * b2 + wy3 * b3;              \
        if (lane < NBIN) {                                                   \
            size_t ob = ((size_t)(M_) * NCH + (unsigned)c0) * NBIN           \
                      + (unsigned)lane;                                      \
            out[ob]        = accA * 0.25f;                                   \
            out[ob + NBIN] = accB * 0.25f;                                   \
        }                                                                    \
    }                                                                        \
} while (0)

#define WAIT10() do {                                                        \
    __builtin_amdgcn_sched_barrier(0);                                       \
    asm volatile("s_waitcnt vmcnt(10)" ::: "memory");                        \
    __builtin_amdgcn_sched_barrier(0);                                       \
} while (0)

// ---------------------------------------------------------------------------
// Main kernel: persistent waves, 1024 blocks x 128 threads (2 waves).
// Wave owns (channel-pair, ROI-chunk); double-buffered LDS pipeline.
// ---------------------------------------------------------------------------
__global__ __launch_bounds__(128, 2) void roi_align_kernel(
    const float* __restrict__ f0, const float* __restrict__ f1,
    const float* __restrict__ f2, const float* __restrict__ f3,
    const unsigned int* __restrict__ tab,
    float* __restrict__ out, int M)
{
    __shared__ float sF[2][WREG];

    const int lane = threadIdx.x & 63;
    const int w    = __builtin_amdgcn_readfirstlane(threadIdx.x >> 6);

    // block b: xcd=b&7 owns cpairs [xcd*16, xcd*16+16); 8 chunk-pairs x 2 waves
    const unsigned b        = blockIdx.x;
    const unsigned xcd      = b & 7u;
    const unsigned id       = b >> 3;            // 0..127
    const unsigned cp_local = id >> 3;           // 0..15
    const unsigned chpair   = id & 7u;           // 0..7
    const int c0   = (int)((xcd * 16u + cp_local) * 2u);
    const int CH   = (M + 15) >> 4;              // ROIs per chunk (16 chunks)
    const int chunk = (int)(chpair * 2u) + w;    // 0..15
    const int m0   = chunk * CH;
    const int mend = min(M, m0 + CH);
    if (m0 >= mend) return;

    const int ci = lane < NBIN ? lane : 0;
    const int py = ci / POOL;
    const int px = ci - POOL * py;

    uint4 X0a, X1a, Y0a, Y1a, S0a, S1a, S2a;
    uint4 X0b, X1b, Y0b, Y1b, S0b, S1b, S2b;

    int m = m0;
    // prologue: geom(m0) -> A, stage(m0) -> buf0, geom(m0+1) -> B
    GEOM(m, X0a, X1a, Y0a, Y1a, S0a, S1a, S2a);
    STAGE(S0a, S1a, S2a, 0);
    {
        int m1 = (m + 1 < mend) ? m + 1 : m;
        GEOM(m1, X0b, X1b, Y0b, Y1b, S0b, S1b, S2b);
    }
    int par = 0;

    while (true) {
        // ---- iter: cur = A ----
        STAGE(S0b, S1b, S2b, par ^ 1);           // staging(m+1) airborne
        WAIT10();                                 // staging(m) retired
        COMPUTE_STORE(X0a, X1a, Y0a, Y1a, S2a, par, m);
        ++m; if (m >= mend) break;
        par ^= 1;
        {
            int m2 = (m + 1 < mend) ? m + 1 : m;
            GEOM(m2, X0a, X1a, Y0a, Y1a, S0a, S1a, S2a);   // A freed -> m+1
        }
        // ---- iter: cur = B ----
        STAGE(S0a, S1a, S2a, par ^ 1);
        WAIT10();
        COMPUTE_STORE(X0b, X1b, Y0b, Y1b, S2b, par, m);
        ++m; if (m >= mend) break;
        par ^= 1;
        {
            int m2 = (m + 1 < mend) ? m + 1 : m;
            GEOM(m2, X0b, X1b, Y0b, Y1b, S0b, S1b, S2b);
        }
    }
    // drain dangling tail stagings before LDS dealloc / wave exit
    asm volatile("s_waitcnt vmcnt(0)" ::: "memory");
}

// ---------------------------------------------------------------------------
// Fallback: unsafe ROIs (compacted list), direct global gather. One unit
// (ROI,channel) per wave per loop step. Exact same arithmetic.
// ---------------------------------------------------------------------------
__global__ __launch_bounds__(256) void roi_fallback_kernel(
    const float* __restrict__ f0, const float* __restrict__ f1,
    const float* __restrict__ f2, const float* __restrict__ f3,
    const unsigned int* __restrict__ tab, const unsigned int* __restrict__ list,
    const unsigned int* __restrict__ cnt,
    float* __restrict__ out, int M)
{
    const int lane = threadIdx.x & 63;
    const unsigned wv = blockIdx.x * 4u + (threadIdx.x >> 6);
    const unsigned nw = gridDim.x * 4u;
    const unsigned total = cnt[0] * 256u;

    const int ci = lane < NBIN ? lane : 0;
    const int py = ci / POOL;
    const int px = ci - POOL * py;

    for (unsigned u = wv; u < total; u += nw) {
        const unsigned mi = list[u >> 8];
        const unsigned c  = u & 255u;
        const unsigned* t = tab + (size_t)mi * TS;

        const uint4 s0 = *(const uint4*)(t);
        const int lvl = (int)s0.y;
        const float* fp = (lvl == 0) ? f0 : (lvl == 1) ? f1
                        : (lvl == 2) ? f2 : f3;
        const float* src = fp + (size_t)(s0.x + c * s0.z);

        const uint4* xt = (const uint4*)(t + 16);
        const uint4* yt = (const uint4*)(t + 72);
        const uint2* yw = (const uint2*)(t + 128);
        const uint4 X0 = xt[2 * px];
        const uint4 X1 = xt[2 * px + 1];
        const uint4 Y0 = yt[2 * py];
        const uint4 Y1 = yt[2 * py + 1];
        const uint2 W0 = yw[2 * py];
        const uint2 W1 = yw[2 * py + 1];

        const unsigned xr0 = X0.x, xp0 = X0.y, xr1 = X1.x, xp1 = X1.y;
        const float wxl0 = __uint_as_float(X0.z), wxh0 = __uint_as_float(X0.w);
        const float wxl1 = __uint_as_float(X1.z), wxh1 = __uint_as_float(X1.w);
        const unsigned ra = W0.x, rb = W0.y, rc = W1.x, rd = W1.y;
        const float wy0 = __uint_as_float(Y0.z), wy1 = __uint_as_float(Y0.w);
        const float wy2 = __uint_as_float(Y1.z), wy3 = __uint_as_float(Y1.w);

        float a0 = src[ra + xr0] * wxl0 + src[ra + xp0] * wxh0
                 + src[ra + xr1] * wxl1 + src[ra + xp1] * wxh1;
        float a1 = src[rb + xr0] * wxl0 + src[rb + xp0] * wxh0
                 + src[rb + xr1] * wxl1 + src[rb + xp1] * wxh1;
        float a2 = src[rc + xr0] * wxl0 + src[rc + xp0] * wxh0
                 + src[rc + xr1] * wxl1 + src[rc + xp1] * wxh1;
        float a3 = src[rd + xr0] * wxl0 + src[rd + xp0] * wxh0
                 + src[rd + xr1] * wxl1 + src[rd + xp1] * wxh1;
        float acc = wy0 * a0 + wy1 * a1 + wy2 * a2 + wy3 * a3;

        if (lane < NBIN) {
            size_t ob = ((size_t)mi * NCH + c) * NBIN + (unsigned)lane;
            out[ob] = acc * 0.25f;
        }
    }
}

extern "C" void kernel_launch(void* const* d_in, const int* in_sizes, int n_in,
                              void* d_out, int out_size, void* d_ws, size_t ws_size,
                              hipStream_t stream) {
    const float* f0    = (const float*)d_in[0];
    const float* f1    = (const float*)d_in[1];
    const float* f2    = (const float*)d_in[2];
    const float* f3    = (const float*)d_in[3];
    const float* boxes = (const float*)d_in[4];
    const int*   bidx  = (const int*)d_in[5];
    float* out = (float*)d_out;

    int M = in_sizes[4] / 4;
    unsigned int* cnt  = (unsigned int*)d_ws;
    unsigned int* list = cnt + 64;                    // up to 8192 ROIs
    unsigned int* tab  = cnt + 64 + 8192;             // M * 640 B

    hipMemsetAsync(d_ws, 0, 4, stream);

    int pblocks = (M + PWPB - 1) / PWPB;
    hipLaunchKernelGGL(roi_precompute_kernel, dim3(pblocks), dim3(256), 0,
                       stream, boxes, bidx, tab, list, cnt, M);

    hipLaunchKernelGGL(roi_align_kernel, dim3(1024), dim3(128), 0, stream,
                       f0, f1, f2, f3, tab, out, M);

    hipLaunchKernelGGL(roi_fallback_kernel, dim3(128), dim3(256), 0, stream,
                       f0, f1, f2, f3, tab, list, cnt, out, M);
}